// Round 4
// baseline (189.991 us; speedup 1.0000x reference)
//
#include <hip/hip_runtime.h>

// One-pole IIR over time, B channels x T samples.
//   out_t = b0*x_t + s_t
//   s_{t+1} = b1*x_t + a1c*out_t = (b1 + a1c*b0)*x_t + a1c*s_t,  a1c = clamp(a1,-1,1)
//
// Fast path (runtime-selected, per-kernel recomputed from a1): |a1c|^WARM <
// 1e-12 => each chunk's carry-in is reconstructed from a WARM-sample window.
// One fused kernel, one read of x, one write of out. Wave-private LDS
// transpose tiles (64ch x 32t), NO block barriers (DS ops in a wave complete
// in order; compiler inserts lgkmcnt waits), stride-36 rows so every LDS
// access is ds_read/write_b128 and bank-uniform, next-subtile global loads
// issued into regs before compute (latency overlap per wave).
// Exact fallback: chunked scan (partials -> chunk scan -> outputs-in-fused).

#define CHUNK 256          // time samples per wave-chunk
#define SUB   32           // subtile width (timesteps)
#define NSUB  (CHUNK / SUB)
#define WARM  32           // warm-up window = one subtile
#define LSTR  36           // padded LDS row stride in floats (16B-aligned rows)

__device__ __forceinline__ float clamp_a1(const float* a1p) {
    return fminf(fmaxf(a1p[0], -1.0f), 1.0f);
}

__device__ __forceinline__ int fast_mode(const float* a1p, int allow) {
    float a1c = clamp_a1(a1p);
    return (allow && powf(fabsf(a1c), (float)WARM) < 1e-12f) ? 1 : 0;
}

// ---------------- exact fallback path ----------------

__global__ void k_partials(const float* __restrict__ x,
                           const float* __restrict__ b0p,
                           const float* __restrict__ b1p,
                           const float* __restrict__ a1p,
                           float* __restrict__ partial,  // [nch][B]
                           int B, int T, int nch, int allow) {
    if (fast_mode(a1p, allow)) return;
    int tid = blockIdx.x * blockDim.x + threadIdx.x;
    int total = B * nch;
    if (tid >= total) return;
    int b = tid / nch;
    int j = tid - b * nch;
    float a1c = clamp_a1(a1p);
    float c = fmaf(a1c, b0p[0], b1p[0]);
    const float4* xp = (const float4*)(x + (size_t)b * T + (size_t)j * CHUNK);
    float s = 0.0f;
#pragma unroll 8
    for (int i = 0; i < CHUNK / 4; ++i) {
        float4 v = xp[i];
        s = fmaf(a1c, s, c * v.x);
        s = fmaf(a1c, s, c * v.y);
        s = fmaf(a1c, s, c * v.z);
        s = fmaf(a1c, s, c * v.w);
    }
    partial[(size_t)j * B + b] = s;
}

__global__ void k_scan(const float* __restrict__ partial,  // [nch][B]
                       const float* __restrict__ state,    // [B]
                       const float* __restrict__ a1p,
                       float* __restrict__ sstart,         // [nch][B]
                       float* __restrict__ final_state,    // [B]
                       int B, int nch, int allow) {
    if (fast_mode(a1p, allow)) return;
    int b = blockIdx.x * blockDim.x + threadIdx.x;
    if (b >= B) return;
    float a1c = clamp_a1(a1p);
    float d = a1c;
    for (int e = 1; e < CHUNK; e <<= 1) d = d * d;  // a1c^CHUNK
    float s = state[b];
    for (int j = 0; j < nch; ++j) {
        sstart[(size_t)j * B + b] = s;
        s = fmaf(d, s, partial[(size_t)j * B + b]);
    }
    final_state[b] = s;
}

// ---------------- main kernel: fast fused path + exact outputs path ----------------

__global__ __launch_bounds__(256, 4)
void k_main(const float* __restrict__ x,
            const float* __restrict__ state,
            const float* __restrict__ b0p,
            const float* __restrict__ b1p,
            const float* __restrict__ a1p,
            const float* __restrict__ sstart,  // [nch][B] (exact mode)
            float* __restrict__ out,           // [B][T]
            float* __restrict__ final_state,   // [B]
            int B, int T, int nch, int allow) {
    const float a1c = clamp_a1(a1p);
    const float b0  = b0p[0];
    const float b1  = b1p[0];

    if (fast_mode(a1p, allow)) {
        __shared__ float lds[4][64][LSTR];  // wave-private 64x32 tiles, b128-aligned rows

        const int w    = threadIdx.x >> 6;
        const int lane = threadIdx.x & 63;
        const int q    = lane >> 3;        // channel sub-index within group of 8
        const int p4   = (lane & 7) << 2;  // 16B slot within 32-float row
        const int nJ   = nch >> 2;
        if (blockIdx.x >= (B >> 6) * nJ) return;
        const int bgrp = blockIdx.x / nJ;
        const int jgrp = blockIdx.x - bgrp * nJ;
        const int j    = (jgrp << 2) + w;
        const int ch0  = bgrp << 6;

        float4 stg[8];

        // ---- warm-up: reconstruct carry-in state from preceding WARM samples ----
        {
            int t0w = (j == 0) ? 0 : j * CHUNK - WARM;  // wave-uniform
#pragma unroll
            for (int r = 0; r < 8; ++r)
                stg[r] = *(const float4*)(x + (size_t)(ch0 + (r << 3) + q) * T + t0w + p4);
#pragma unroll
            for (int r = 0; r < 8; ++r)
                *(float4*)&lds[w][(r << 3) + q][p4] = stg[r];
        }
        float s;
        {
            const float4* row = (const float4*)&lds[w][lane][0];
            float cwm = fmaf(a1c, b0, b1);
            float sw = 0.0f;
#pragma unroll
            for (int i = 0; i < 8; ++i) {
                float4 v = row[i];
                sw = fmaf(a1c, sw, cwm * v.x);
                sw = fmaf(a1c, sw, cwm * v.y);
                sw = fmaf(a1c, sw, cwm * v.z);
                sw = fmaf(a1c, sw, cwm * v.w);
            }
            s = (j == 0) ? state[ch0 + lane] : sw;
        }

        // ---- main loop: barrier-free wave-private pipeline ----
        const int t0 = j * CHUNK;
#pragma unroll
        for (int r = 0; r < 8; ++r)  // preload subtile 0
            stg[r] = *(const float4*)(x + (size_t)(ch0 + (r << 3) + q) * T + t0 + p4);

        for (int sub = 0; sub < NSUB; ++sub) {
            // commit staged subtile to LDS (overwrites tile AFTER prior store reads: in-order DS)
#pragma unroll
            for (int r = 0; r < 8; ++r)
                *(float4*)&lds[w][(r << 3) + q][p4] = stg[r];

            // issue next subtile's global loads early (hide HBM latency under compute)
            if (sub + 1 < NSUB) {
                int t1 = t0 + (sub + 1) * SUB;
#pragma unroll
                for (int r = 0; r < 8; ++r)
                    stg[r] = *(const float4*)(x + (size_t)(ch0 + (r << 3) + q) * T + t1 + p4);
            }

            // compute: lane owns one channel row; in-place x -> out
            {
                float4* row = (float4*)&lds[w][lane][0];
                float4 vv[8];
#pragma unroll
                for (int i = 0; i < 8; ++i) vv[i] = row[i];
#pragma unroll
                for (int i = 0; i < 8; ++i) {
                    float4 v = vv[i];
                    float4 o;
                    o.x = fmaf(b0, v.x, s); s = fmaf(b1, v.x, a1c * o.x);
                    o.y = fmaf(b0, v.y, s); s = fmaf(b1, v.y, a1c * o.y);
                    o.z = fmaf(b0, v.z, s); s = fmaf(b1, v.z, a1c * o.z);
                    o.w = fmaf(b0, v.w, s); s = fmaf(b1, v.w, a1c * o.w);
                    row[i] = o;
                }
            }

            // store: transposed read-back, fully coalesced global writes
            {
                int ts = t0 + sub * SUB;
#pragma unroll
                for (int r = 0; r < 8; ++r) {
                    float4 ov = *(const float4*)&lds[w][(r << 3) + q][p4];
                    *(float4*)(out + (size_t)(ch0 + (r << 3) + q) * T + ts + p4) = ov;
                }
            }
        }

        if (j == nch - 1) final_state[ch0 + lane] = s;
    } else {
        // ---- exact outputs path ----
        int tid = blockIdx.x * blockDim.x + threadIdx.x;
        int total = B * nch;
        if (tid >= total) return;
        int b = tid / nch;
        int j = tid - b * nch;
        float s = sstart[(size_t)j * B + b];
        const float4* xp = (const float4*)(x + (size_t)b * T + (size_t)j * CHUNK);
        float4* op = (float4*)(out + (size_t)b * T + (size_t)j * CHUNK);
#pragma unroll 4
        for (int i = 0; i < CHUNK / 4; ++i) {
            float4 v = xp[i];
            float4 o;
            o.x = fmaf(b0, v.x, s); s = fmaf(b1, v.x, a1c * o.x);
            o.y = fmaf(b0, v.y, s); s = fmaf(b1, v.y, a1c * o.y);
            o.z = fmaf(b0, v.z, s); s = fmaf(b1, v.z, a1c * o.z);
            o.w = fmaf(b0, v.w, s); s = fmaf(b1, v.w, a1c * o.w);
            op[i] = o;
        }
    }
}

extern "C" void kernel_launch(void* const* d_in, const int* in_sizes, int n_in,
                              void* d_out, int out_size, void* d_ws, size_t ws_size,
                              hipStream_t stream) {
    const float* x     = (const float*)d_in[0];
    const float* state = (const float*)d_in[1];
    const float* b0p   = (const float*)d_in[2];
    const float* b1p   = (const float*)d_in[3];
    const float* a1p   = (const float*)d_in[4];

    int B = in_sizes[1];                 // 4096
    int T = in_sizes[0] / B;             // 16384
    int nch = T / CHUNK;                 // 64

    float* out         = (float*)d_out;                   // [B][T]
    float* final_state = (float*)d_out + (size_t)B * T;   // [B]

    // ws layout: partial [nch][B]; then sstart [nch][B]
    float* partial = (float*)d_ws;
    float* sstart  = partial + (size_t)nch * B;

    int allow = (B % 64 == 0) && (T % CHUNK == 0) && (nch % 4 == 0) && (nch * CHUNK == T);

    int block = 256;
    int total = B * nch;
    int grid_exact = (total + block - 1) / block;
    int grid_fast  = allow ? (B / 64) * (nch / 4) : 0;
    int grid_main  = grid_exact > grid_fast ? grid_exact : grid_fast;

    // exact fallback (early-exits in fast mode)
    k_partials<<<grid_exact, block, 0, stream>>>(x, b0p, b1p, a1p, partial,
                                                 B, T, nch, allow);
    k_scan<<<(B + block - 1) / block, block, 0, stream>>>(partial, state, a1p,
                                                          sstart, final_state,
                                                          B, nch, allow);
    // main: fast fused path or exact outputs
    k_main<<<grid_main, block, 0, stream>>>(x, state, b0p, b1p, a1p, sstart,
                                            out, final_state, B, T, nch, allow);
}

// Round 5
// 129.641 us; speedup vs baseline: 1.4655x; 1.4655x over previous
//
#include <hip/hip_runtime.h>

// One-pole IIR over time, B channels x T samples.
//   out_t = b0*x_t + s_t
//   s_{t+1} = b1*x_t + a1c*out_t = (b1 + a1c*b0)*x_t + a1c*s_t,  a1c = clamp(a1,-1,1)
//
// Fast path (runtime-selected from a1 inside each kernel): |a1c|^WARM < 1e-12
// => each chunk's carry-in is reconstructed from a WARM-sample window.
// One fused kernel: one read of x, one write of out. Wave-private LDS
// transpose tiles (64ch x 32t), stride-33 rows (bank (c+t)%32 -> 2 lanes/bank
// = conflict-free; round 4's stride-36 b128 layout was 8-way conflicted and
// regressed). Barrier-free (DS ops in-order within a wave; tiles are
// wave-private). Next subtile prefetched into registers before compute.
// Exact fallback: chunked scan (partials -> chunk scan -> outputs in k_main).

#define CHUNK 256          // time samples per wave-chunk
#define SUB   32           // subtile width (timesteps)
#define NSUB  (CHUNK / SUB)
#define WARM  32           // warm-up window = one subtile
#define LSTR  33           // LDS row stride in floats: bank = (row + col) % 32

__device__ __forceinline__ float clamp_a1(const float* a1p) {
    return fminf(fmaxf(a1p[0], -1.0f), 1.0f);
}

__device__ __forceinline__ int fast_mode(const float* a1p, int allow) {
    float a1c = clamp_a1(a1p);
    return (allow && powf(fabsf(a1c), (float)WARM) < 1e-12f) ? 1 : 0;
}

// ---------------- exact fallback path ----------------

__global__ void k_partials(const float* __restrict__ x,
                           const float* __restrict__ b0p,
                           const float* __restrict__ b1p,
                           const float* __restrict__ a1p,
                           float* __restrict__ partial,  // [nch][B]
                           int B, int T, int nch, int allow) {
    if (fast_mode(a1p, allow)) return;
    int tid = blockIdx.x * blockDim.x + threadIdx.x;
    int total = B * nch;
    if (tid >= total) return;
    int b = tid / nch;
    int j = tid - b * nch;
    float a1c = clamp_a1(a1p);
    float c = fmaf(a1c, b0p[0], b1p[0]);
    const float4* xp = (const float4*)(x + (size_t)b * T + (size_t)j * CHUNK);
    float s = 0.0f;
#pragma unroll 8
    for (int i = 0; i < CHUNK / 4; ++i) {
        float4 v = xp[i];
        s = fmaf(a1c, s, c * v.x);
        s = fmaf(a1c, s, c * v.y);
        s = fmaf(a1c, s, c * v.z);
        s = fmaf(a1c, s, c * v.w);
    }
    partial[(size_t)j * B + b] = s;
}

__global__ void k_scan(const float* __restrict__ partial,  // [nch][B]
                       const float* __restrict__ state,    // [B]
                       const float* __restrict__ a1p,
                       float* __restrict__ sstart,         // [nch][B]
                       float* __restrict__ final_state,    // [B]
                       int B, int nch, int allow) {
    if (fast_mode(a1p, allow)) return;
    int b = blockIdx.x * blockDim.x + threadIdx.x;
    if (b >= B) return;
    float a1c = clamp_a1(a1p);
    float d = a1c;
    for (int e = 1; e < CHUNK; e <<= 1) d = d * d;  // a1c^CHUNK
    float s = state[b];
    for (int j = 0; j < nch; ++j) {
        sstart[(size_t)j * B + b] = s;
        s = fmaf(d, s, partial[(size_t)j * B + b]);
    }
    final_state[b] = s;
}

// ---------------- main kernel: fast fused path + exact outputs path ----------------

__global__ __launch_bounds__(256, 4)
void k_main(const float* __restrict__ x,
            const float* __restrict__ state,
            const float* __restrict__ b0p,
            const float* __restrict__ b1p,
            const float* __restrict__ a1p,
            const float* __restrict__ sstart,  // [nch][B] (exact mode)
            float* __restrict__ out,           // [B][T]
            float* __restrict__ final_state,   // [B]
            int B, int T, int nch, int allow) {
    const float a1c = clamp_a1(a1p);
    const float b0  = b0p[0];
    const float b1  = b1p[0];

    if (fast_mode(a1p, allow)) {
        __shared__ float lds[4][64][LSTR];  // wave-private 64x32 tiles

        const int w    = threadIdx.x >> 6;
        const int lane = threadIdx.x & 63;
        const int q    = lane >> 3;        // channel sub-index within group of 8
        const int p4   = (lane & 7) << 2;  // 16B slot within 32-float row
        const int nJ   = nch >> 2;
        if (blockIdx.x >= (B >> 6) * nJ) return;
        const int bgrp = blockIdx.x / nJ;
        const int jgrp = blockIdx.x - bgrp * nJ;
        const int j    = (jgrp << 2) + w;
        const int ch0  = bgrp << 6;
        const int t0   = j * CHUNK;

        float4 stg[8];

        // ---- warm-up loads -> LDS ----
        {
            int t0w = (j == 0) ? 0 : t0 - WARM;  // wave-uniform
#pragma unroll
            for (int r = 0; r < 8; ++r)
                stg[r] = *(const float4*)(x + (size_t)(ch0 + (r << 3) + q) * T + t0w + p4);
#pragma unroll
            for (int r = 0; r < 8; ++r) {
                int c = (r << 3) + q;
                lds[w][c][p4]     = stg[r].x;
                lds[w][c][p4 + 1] = stg[r].y;
                lds[w][c][p4 + 2] = stg[r].z;
                lds[w][c][p4 + 3] = stg[r].w;
            }
        }

        // prefetch subtile 0 while the warm-up reduction runs
#pragma unroll
        for (int r = 0; r < 8; ++r)
            stg[r] = *(const float4*)(x + (size_t)(ch0 + (r << 3) + q) * T + t0 + p4);

        // ---- warm-up reduction: carry-in state for this chunk ----
        float s;
        {
            float cwm = fmaf(a1c, b0, b1);
            float sw = 0.0f;
            float v[SUB];
#pragma unroll
            for (int t = 0; t < SUB; ++t) v[t] = lds[w][lane][t];
#pragma unroll
            for (int t = 0; t < SUB; ++t) sw = fmaf(a1c, sw, cwm * v[t]);
            s = (j == 0) ? state[ch0 + lane] : sw;
        }

        // ---- main loop: barrier-free wave-private pipeline ----
        for (int sub = 0; sub < NSUB; ++sub) {
            // commit staged subtile to LDS (in-order DS: prior readback done)
#pragma unroll
            for (int r = 0; r < 8; ++r) {
                int c = (r << 3) + q;
                lds[w][c][p4]     = stg[r].x;
                lds[w][c][p4 + 1] = stg[r].y;
                lds[w][c][p4 + 2] = stg[r].z;
                lds[w][c][p4 + 3] = stg[r].w;
            }

            // issue next subtile's global loads (hide HBM latency under compute)
            if (sub + 1 < NSUB) {
                int t1 = t0 + (sub + 1) * SUB;
#pragma unroll
                for (int r = 0; r < 8; ++r)
                    stg[r] = *(const float4*)(x + (size_t)(ch0 + (r << 3) + q) * T + t1 + p4);
            }

            // compute: lane owns one channel row; in-place x -> out
            {
                float v[SUB];
#pragma unroll
                for (int t = 0; t < SUB; ++t) v[t] = lds[w][lane][t];
#pragma unroll
                for (int t = 0; t < SUB; ++t) {
                    float o = fmaf(b0, v[t], s);
                    s = fmaf(b1, v[t], a1c * o);
                    lds[w][lane][t] = o;
                }
            }

            // store: transposed read-back, fully coalesced global writes
            {
                int ts = t0 + sub * SUB;
#pragma unroll
                for (int r = 0; r < 8; ++r) {
                    int c = (r << 3) + q;
                    float4 ov;
                    ov.x = lds[w][c][p4];
                    ov.y = lds[w][c][p4 + 1];
                    ov.z = lds[w][c][p4 + 2];
                    ov.w = lds[w][c][p4 + 3];
                    *(float4*)(out + (size_t)(ch0 + c) * T + ts + p4) = ov;
                }
            }
        }

        if (j == nch - 1) final_state[ch0 + lane] = s;
    } else {
        // ---- exact outputs path ----
        int tid = blockIdx.x * blockDim.x + threadIdx.x;
        int total = B * nch;
        if (tid >= total) return;
        int b = tid / nch;
        int j = tid - b * nch;
        float s = sstart[(size_t)j * B + b];
        const float4* xp = (const float4*)(x + (size_t)b * T + (size_t)j * CHUNK);
        float4* op = (float4*)(out + (size_t)b * T + (size_t)j * CHUNK);
#pragma unroll 4
        for (int i = 0; i < CHUNK / 4; ++i) {
            float4 v = xp[i];
            float4 o;
            o.x = fmaf(b0, v.x, s); s = fmaf(b1, v.x, a1c * o.x);
            o.y = fmaf(b0, v.y, s); s = fmaf(b1, v.y, a1c * o.y);
            o.z = fmaf(b0, v.z, s); s = fmaf(b1, v.z, a1c * o.z);
            o.w = fmaf(b0, v.w, s); s = fmaf(b1, v.w, a1c * o.w);
            op[i] = o;
        }
    }
}

extern "C" void kernel_launch(void* const* d_in, const int* in_sizes, int n_in,
                              void* d_out, int out_size, void* d_ws, size_t ws_size,
                              hipStream_t stream) {
    const float* x     = (const float*)d_in[0];
    const float* state = (const float*)d_in[1];
    const float* b0p   = (const float*)d_in[2];
    const float* b1p   = (const float*)d_in[3];
    const float* a1p   = (const float*)d_in[4];

    int B = in_sizes[1];                 // 4096
    int T = in_sizes[0] / B;             // 16384
    int nch = T / CHUNK;                 // 64

    float* out         = (float*)d_out;                   // [B][T]
    float* final_state = (float*)d_out + (size_t)B * T;   // [B]

    // ws layout: partial [nch][B]; then sstart [nch][B]
    float* partial = (float*)d_ws;
    float* sstart  = partial + (size_t)nch * B;

    int allow = (B % 64 == 0) && (T % CHUNK == 0) && (nch % 4 == 0) && (nch * CHUNK == T);

    int block = 256;
    int total = B * nch;
    int grid_exact = (total + block - 1) / block;
    int grid_fast  = allow ? (B / 64) * (nch / 4) : 0;
    int grid_main  = grid_exact > grid_fast ? grid_exact : grid_fast;

    // exact fallback (early-exits in fast mode)
    k_partials<<<grid_exact, block, 0, stream>>>(x, b0p, b1p, a1p, partial,
                                                 B, T, nch, allow);
    k_scan<<<(B + block - 1) / block, block, 0, stream>>>(partial, state, a1p,
                                                          sstart, final_state,
                                                          B, nch, allow);
    // main: fast fused path or exact outputs
    k_main<<<grid_main, block, 0, stream>>>(x, state, b0p, b1p, a1p, sstart,
                                            out, final_state, B, T, nch, allow);
}

// Round 6
// 126.504 us; speedup vs baseline: 1.5019x; 1.0248x over previous
//
#include <hip/hip_runtime.h>

// One-pole IIR over time, B channels x T samples.
//   out_t = b0*x_t + s_t
//   s_{t+1} = b1*x_t + a1c*out_t = (b1 + a1c*b0)*x_t + a1c*s_t,  a1c = clamp(a1,-1,1)
//
// Fast path (runtime-selected from a1 inside each kernel): |a1c|^WARM < 1e-12
// => each chunk's carry-in is reconstructed from a WARM-sample window.
// One fused kernel: one read of x, one write of out. Wave-private LDS
// transpose tiles (64ch x 32t), stride-33 rows (bank (c+t)%32, 2 lanes/bank =
// conflict-free, measured 0 conflicts r5). Barrier-free (DS in-order within a
// wave; tiles wave-private). Pipeline: compute(k) -> store(k) -> commit(k+1)
// -> prefetch(k+2): prefetch->use distance = one full iteration (> HBM lat).
// Recurrence in 1-FMA-chain form: s' = a1c*s + c*x, c = b1 + a1c*b0.
// 2-wave blocks: 16.9 KB LDS -> 9 blocks/CU -> 18 waves/CU (VGPR<=64).
// Exact fallback: chunked scan (partials -> chunk scan -> outputs in k_main).

#define CHUNK 256          // time samples per wave-chunk
#define SUB   32           // subtile width (timesteps)
#define NSUB  (CHUNK / SUB)
#define WARM  32           // warm-up window = one subtile
#define LSTR  33           // LDS row stride in floats: bank = (row + col) % 32
#define BLKW  2            // waves per block
#define BLKT  (64 * BLKW)  // threads per block

__device__ __forceinline__ float clamp_a1(const float* a1p) {
    return fminf(fmaxf(a1p[0], -1.0f), 1.0f);
}

__device__ __forceinline__ int fast_mode(const float* a1p, int allow) {
    float a1c = clamp_a1(a1p);
    return (allow && powf(fabsf(a1c), (float)WARM) < 1e-12f) ? 1 : 0;
}

// ---------------- exact fallback path ----------------

__global__ void k_partials(const float* __restrict__ x,
                           const float* __restrict__ b0p,
                           const float* __restrict__ b1p,
                           const float* __restrict__ a1p,
                           float* __restrict__ partial,  // [nch][B]
                           int B, int T, int nch, int allow) {
    if (fast_mode(a1p, allow)) return;
    int tid = blockIdx.x * blockDim.x + threadIdx.x;
    int total = B * nch;
    if (tid >= total) return;
    int b = tid / nch;
    int j = tid - b * nch;
    float a1c = clamp_a1(a1p);
    float c = fmaf(a1c, b0p[0], b1p[0]);
    const float4* xp = (const float4*)(x + (size_t)b * T + (size_t)j * CHUNK);
    float s = 0.0f;
#pragma unroll 8
    for (int i = 0; i < CHUNK / 4; ++i) {
        float4 v = xp[i];
        s = fmaf(a1c, s, c * v.x);
        s = fmaf(a1c, s, c * v.y);
        s = fmaf(a1c, s, c * v.z);
        s = fmaf(a1c, s, c * v.w);
    }
    partial[(size_t)j * B + b] = s;
}

__global__ void k_scan(const float* __restrict__ partial,  // [nch][B]
                       const float* __restrict__ state,    // [B]
                       const float* __restrict__ a1p,
                       float* __restrict__ sstart,         // [nch][B]
                       float* __restrict__ final_state,    // [B]
                       int B, int nch, int allow) {
    if (fast_mode(a1p, allow)) return;
    int b = blockIdx.x * blockDim.x + threadIdx.x;
    if (b >= B) return;
    float a1c = clamp_a1(a1p);
    float d = a1c;
    for (int e = 1; e < CHUNK; e <<= 1) d = d * d;  // a1c^CHUNK
    float s = state[b];
    for (int j = 0; j < nch; ++j) {
        sstart[(size_t)j * B + b] = s;
        s = fmaf(d, s, partial[(size_t)j * B + b]);
    }
    final_state[b] = s;
}

// ---------------- main kernel: fast fused path + exact outputs path ----------------

__global__ __launch_bounds__(BLKT, 4)
void k_main(const float* __restrict__ x,
            const float* __restrict__ state,
            const float* __restrict__ b0p,
            const float* __restrict__ b1p,
            const float* __restrict__ a1p,
            const float* __restrict__ sstart,  // [nch][B] (exact mode)
            float* __restrict__ out,           // [B][T]
            float* __restrict__ final_state,   // [B]
            int B, int T, int nch, int allow) {
    const float a1c = clamp_a1(a1p);
    const float b0  = b0p[0];
    const float b1  = b1p[0];

    if (fast_mode(a1p, allow)) {
        __shared__ float lds[BLKW][64][LSTR];  // wave-private 64x32 tiles

        const int w    = threadIdx.x >> 6;
        const int lane = threadIdx.x & 63;
        const int q    = lane >> 3;        // channel sub-index within group of 8
        const int p4   = (lane & 7) << 2;  // 16B slot within 32-float row
        const int nJ   = nch / BLKW;
        if (blockIdx.x >= (B >> 6) * nJ) return;
        const int bgrp = blockIdx.x / nJ;
        const int jgrp = blockIdx.x - bgrp * nJ;
        const int j    = jgrp * BLKW + w;
        const int ch0  = bgrp << 6;
        const int t0   = j * CHUNK;
        const float c  = fmaf(a1c, b0, b1);

        float4 stg[8];

#define PREFETCH(TT)                                                            \
        _Pragma("unroll")                                                       \
        for (int r = 0; r < 8; ++r)                                             \
            stg[r] = *(const float4*)(x + (size_t)(ch0 + (r << 3) + q) * T + (TT) + p4);

#define COMMIT()                                                                \
        _Pragma("unroll")                                                       \
        for (int r = 0; r < 8; ++r) {                                           \
            int cc = (r << 3) + q;                                              \
            lds[w][cc][p4]     = stg[r].x;                                      \
            lds[w][cc][p4 + 1] = stg[r].y;                                      \
            lds[w][cc][p4 + 2] = stg[r].z;                                      \
            lds[w][cc][p4 + 3] = stg[r].w;                                      \
        }

        // ---- warm-up loads -> LDS ----
        {
            int t0w = (j == 0) ? 0 : t0 - WARM;  // wave-uniform
            PREFETCH(t0w)
            COMMIT()
        }

        // prefetch subtile 0 (latency hides under the warm-up reduction)
        PREFETCH(t0)

        // ---- warm-up reduction: carry-in state for this chunk ----
        float s;
        {
            float sw = 0.0f;
            float v[WARM];
#pragma unroll
            for (int t = 0; t < WARM; ++t) v[t] = lds[w][lane][t];
#pragma unroll
            for (int t = 0; t < WARM; ++t) sw = fmaf(a1c, sw, c * v[t]);
            s = (j == 0) ? state[ch0 + lane] : sw;
        }

        // commit subtile 0, prefetch subtile 1
        COMMIT()
        PREFETCH(t0 + SUB)

        // ---- main loop: compute(k) -> store(k) -> commit(k+1) -> prefetch(k+2) ----
        for (int sub = 0; sub < NSUB; ++sub) {
            // compute: lane owns one channel row; 1-FMA dependent chain;
            // two 16-register halves keep VGPR pressure low
#pragma unroll
            for (int h = 0; h < 2; ++h) {
                float v[16];
#pragma unroll
                for (int t = 0; t < 16; ++t) v[t] = lds[w][lane][(h << 4) + t];
#pragma unroll
                for (int t = 0; t < 16; ++t) {
                    float o = fmaf(b0, v[t], s);     // off-chain
                    lds[w][lane][(h << 4) + t] = o;
                    s = fmaf(a1c, s, c * v[t]);      // chain: 1 FMA/sample
                }
            }

            // store: transposed read-back, fully coalesced global writes
            {
                int ts = t0 + sub * SUB;
#pragma unroll
                for (int r = 0; r < 8; ++r) {
                    int cc = (r << 3) + q;
                    float4 ov;
                    ov.x = lds[w][cc][p4];
                    ov.y = lds[w][cc][p4 + 1];
                    ov.z = lds[w][cc][p4 + 2];
                    ov.w = lds[w][cc][p4 + 3];
                    *(float4*)(out + (size_t)(ch0 + cc) * T + ts + p4) = ov;
                }
            }

            // commit next subtile (its loads were issued a FULL iteration ago),
            // then issue loads two subtiles ahead
            if (sub + 1 < NSUB) {
                COMMIT()
                if (sub + 2 < NSUB) {
                    PREFETCH(t0 + (sub + 2) * SUB)
                }
            }
        }

        if (j == nch - 1) final_state[ch0 + lane] = s;
#undef PREFETCH
#undef COMMIT
    } else {
        // ---- exact outputs path ----
        int tid = blockIdx.x * blockDim.x + threadIdx.x;
        int total = B * nch;
        if (tid >= total) return;
        int b = tid / nch;
        int j = tid - b * nch;
        float s = sstart[(size_t)j * B + b];
        const float4* xp = (const float4*)(x + (size_t)b * T + (size_t)j * CHUNK);
        float4* op = (float4*)(out + (size_t)b * T + (size_t)j * CHUNK);
#pragma unroll 4
        for (int i = 0; i < CHUNK / 4; ++i) {
            float4 v = xp[i];
            float4 o;
            o.x = fmaf(b0, v.x, s); s = fmaf(b1, v.x, a1c * o.x);
            o.y = fmaf(b0, v.y, s); s = fmaf(b1, v.y, a1c * o.y);
            o.z = fmaf(b0, v.z, s); s = fmaf(b1, v.z, a1c * o.z);
            o.w = fmaf(b0, v.w, s); s = fmaf(b1, v.w, a1c * o.w);
            op[i] = o;
        }
    }
}

extern "C" void kernel_launch(void* const* d_in, const int* in_sizes, int n_in,
                              void* d_out, int out_size, void* d_ws, size_t ws_size,
                              hipStream_t stream) {
    const float* x     = (const float*)d_in[0];
    const float* state = (const float*)d_in[1];
    const float* b0p   = (const float*)d_in[2];
    const float* b1p   = (const float*)d_in[3];
    const float* a1p   = (const float*)d_in[4];

    int B = in_sizes[1];                 // 4096
    int T = in_sizes[0] / B;             // 16384
    int nch = T / CHUNK;                 // 64

    float* out         = (float*)d_out;                   // [B][T]
    float* final_state = (float*)d_out + (size_t)B * T;   // [B]

    // ws layout: partial [nch][B]; then sstart [nch][B]
    float* partial = (float*)d_ws;
    float* sstart  = partial + (size_t)nch * B;

    int allow = (B % 64 == 0) && (T % CHUNK == 0) && (nch % BLKW == 0) &&
                (nch * CHUNK == T);

    int total = B * nch;
    int grid_exact = (total + BLKT - 1) / BLKT;
    int grid_fast  = allow ? (B / 64) * (nch / BLKW) : 0;
    int grid_main  = grid_exact > grid_fast ? grid_exact : grid_fast;

    // exact fallback (early-exits in fast mode)
    k_partials<<<(total + 255) / 256, 256, 0, stream>>>(x, b0p, b1p, a1p, partial,
                                                        B, T, nch, allow);
    k_scan<<<(B + 255) / 256, 256, 0, stream>>>(partial, state, a1p,
                                                sstart, final_state, B, nch, allow);
    // main: fast fused path or exact outputs
    k_main<<<grid_main, BLKT, 0, stream>>>(x, state, b0p, b1p, a1p, sstart,
                                           out, final_state, B, T, nch, allow);
}

// Round 7
// 106.700 us; speedup vs baseline: 1.7806x; 1.1856x over previous
//
#include <hip/hip_runtime.h>

// One-pole IIR over time, B channels x T samples.
//   out_t = b0*x_t + s_t
//   s_{t+1} = b1*x_t + a1c*out_t = (b1 + a1c*b0)*x_t + a1c*s_t,  a1c = clamp(a1,-1,1)
//
// Fast path (runtime-selected from a1 inside each kernel): |a1c|^WARM < 1e-12
// => each chunk's carry-in is reconstructed from a WARM-sample window.
// One fused kernel: one read of x, one write of out. Wave-private LDS
// transpose tiles (64ch x 32t), stride-33 rows (bank (c+t)%32, 2 lanes/bank =
// conflict-free, measured 0 conflicts r5/r6). Barrier-free (DS in-order within
// a wave; tiles wave-private).
// r7: 2-deep register ping-pong prefetch (subtile k in buf k%2), loop fully
// unrolled (static buffer indices) ordered commit(k) -> prefetch(k+2) ->
// compute(k) -> store(k): the compiler emits COUNTED vmcnt waits (only buf-k's
// loads) and prefetch->use distance is ~2 iterations >> HBM latency.
// Output stores are non-temporal (out never re-read; keep x in L3).
// Exact fallback: chunked scan (partials -> chunk scan -> outputs in k_main).

#define CHUNK 256          // time samples per wave-chunk
#define SUB   32           // subtile width (timesteps)
#define NSUB  (CHUNK / SUB)
#define WARM  32           // warm-up window = one subtile
#define LSTR  33           // LDS row stride in floats: bank = (row + col) % 32
#define BLKW  2            // waves per block
#define BLKT  (64 * BLKW)  // threads per block

typedef float f32x4 __attribute__((ext_vector_type(4)));

__device__ __forceinline__ float clamp_a1(const float* a1p) {
    return fminf(fmaxf(a1p[0], -1.0f), 1.0f);
}

__device__ __forceinline__ int fast_mode(const float* a1p, int allow) {
    float a1c = clamp_a1(a1p);
    return (allow && powf(fabsf(a1c), (float)WARM) < 1e-12f) ? 1 : 0;
}

// ---------------- exact fallback path ----------------

__global__ void k_partials(const float* __restrict__ x,
                           const float* __restrict__ b0p,
                           const float* __restrict__ b1p,
                           const float* __restrict__ a1p,
                           float* __restrict__ partial,  // [nch][B]
                           int B, int T, int nch, int allow) {
    if (fast_mode(a1p, allow)) return;
    int tid = blockIdx.x * blockDim.x + threadIdx.x;
    int total = B * nch;
    if (tid >= total) return;
    int b = tid / nch;
    int j = tid - b * nch;
    float a1c = clamp_a1(a1p);
    float c = fmaf(a1c, b0p[0], b1p[0]);
    const float4* xp = (const float4*)(x + (size_t)b * T + (size_t)j * CHUNK);
    float s = 0.0f;
#pragma unroll 8
    for (int i = 0; i < CHUNK / 4; ++i) {
        float4 v = xp[i];
        s = fmaf(a1c, s, c * v.x);
        s = fmaf(a1c, s, c * v.y);
        s = fmaf(a1c, s, c * v.z);
        s = fmaf(a1c, s, c * v.w);
    }
    partial[(size_t)j * B + b] = s;
}

__global__ void k_scan(const float* __restrict__ partial,  // [nch][B]
                       const float* __restrict__ state,    // [B]
                       const float* __restrict__ a1p,
                       float* __restrict__ sstart,         // [nch][B]
                       float* __restrict__ final_state,    // [B]
                       int B, int nch, int allow) {
    if (fast_mode(a1p, allow)) return;
    int b = blockIdx.x * blockDim.x + threadIdx.x;
    if (b >= B) return;
    float a1c = clamp_a1(a1p);
    float d = a1c;
    for (int e = 1; e < CHUNK; e <<= 1) d = d * d;  // a1c^CHUNK
    float s = state[b];
    for (int j = 0; j < nch; ++j) {
        sstart[(size_t)j * B + b] = s;
        s = fmaf(d, s, partial[(size_t)j * B + b]);
    }
    final_state[b] = s;
}

// ---------------- main kernel: fast fused path + exact outputs path ----------------

__global__ __launch_bounds__(BLKT, 4)
void k_main(const float* __restrict__ x,
            const float* __restrict__ state,
            const float* __restrict__ b0p,
            const float* __restrict__ b1p,
            const float* __restrict__ a1p,
            const float* __restrict__ sstart,  // [nch][B] (exact mode)
            float* __restrict__ out,           // [B][T]
            float* __restrict__ final_state,   // [B]
            int B, int T, int nch, int allow) {
    const float a1c = clamp_a1(a1p);
    const float b0  = b0p[0];
    const float b1  = b1p[0];

    if (fast_mode(a1p, allow)) {
        __shared__ float lds[BLKW][64][LSTR];  // wave-private 64x32 tiles

        const int w    = threadIdx.x >> 6;
        const int lane = threadIdx.x & 63;
        const int q    = lane >> 3;        // channel sub-index within group of 8
        const int p4   = (lane & 7) << 2;  // 16B slot within 32-float row
        const int nJ   = nch / BLKW;
        if (blockIdx.x >= (B >> 6) * nJ) return;
        const int bgrp = blockIdx.x / nJ;
        const int jgrp = blockIdx.x - bgrp * nJ;
        const int j    = jgrp * BLKW + w;
        const int ch0  = bgrp << 6;
        const int t0   = j * CHUNK;
        const float c  = fmaf(a1c, b0, b1);

        float4 stgA[8], stgB[8];

#define PF(BUF, TT)                                                             \
        _Pragma("unroll")                                                       \
        for (int r = 0; r < 8; ++r)                                             \
            BUF[r] = *(const float4*)(x + (size_t)(ch0 + (r << 3) + q) * T + (TT) + p4);

#define CM(BUF)                                                                 \
        _Pragma("unroll")                                                       \
        for (int r = 0; r < 8; ++r) {                                           \
            int cc = (r << 3) + q;                                              \
            lds[w][cc][p4]     = BUF[r].x;                                      \
            lds[w][cc][p4 + 1] = BUF[r].y;                                      \
            lds[w][cc][p4 + 2] = BUF[r].z;                                      \
            lds[w][cc][p4 + 3] = BUF[r].w;                                      \
        }

        // ---- warm-up loads -> LDS; prefetch subtiles 0 and 1 before the
        //      warm-up VALU reduction so their latency hides under it ----
        {
            int t0w = (j == 0) ? 0 : t0 - WARM;  // wave-uniform
            PF(stgA, t0w)
            CM(stgA)
        }
        PF(stgA, t0)          // subtile 0 -> buf A (A's regs free after commit)
        PF(stgB, t0 + SUB)    // subtile 1 -> buf B

        // ---- warm-up reduction: carry-in state for this chunk ----
        float s;
        {
            float sw = 0.0f;
            float v[WARM];
#pragma unroll
            for (int t = 0; t < WARM; ++t) v[t] = lds[w][lane][t];
#pragma unroll
            for (int t = 0; t < WARM; ++t) sw = fmaf(a1c, sw, c * v[t]);
            s = (j == 0) ? state[ch0 + lane] : sw;
        }

        // ---- main loop: commit(k) -> prefetch(k+2) -> compute(k) -> store(k)
        //      fully unrolled: static buffer selection, counted vmcnt waits ----
#pragma unroll
        for (int sub = 0; sub < NSUB; ++sub) {
            // commit subtile k (waits only on its own buffer's loads)
            if (sub & 1) { CM(stgB) } else { CM(stgA) }

            // prefetch subtile k+2 into the buffer just drained
            if (sub + 2 < NSUB) {
                if (sub & 1) { PF(stgB, t0 + (sub + 2) * SUB) }
                else         { PF(stgA, t0 + (sub + 2) * SUB) }
            }

            // compute: lane owns one channel row; 1-FMA dependent chain
#pragma unroll
            for (int h = 0; h < 2; ++h) {
                float v[16];
#pragma unroll
                for (int t = 0; t < 16; ++t) v[t] = lds[w][lane][(h << 4) + t];
#pragma unroll
                for (int t = 0; t < 16; ++t) {
                    float o = fmaf(b0, v[t], s);     // off-chain
                    lds[w][lane][(h << 4) + t] = o;
                    s = fmaf(a1c, s, c * v[t]);      // chain: 1 FMA/sample
                }
            }

            // store: transposed read-back, coalesced non-temporal global writes
            {
                int ts = t0 + sub * SUB;
#pragma unroll
                for (int r = 0; r < 8; ++r) {
                    int cc = (r << 3) + q;
                    f32x4 ov;
                    ov.x = lds[w][cc][p4];
                    ov.y = lds[w][cc][p4 + 1];
                    ov.z = lds[w][cc][p4 + 2];
                    ov.w = lds[w][cc][p4 + 3];
                    __builtin_nontemporal_store(
                        ov, (f32x4*)(out + (size_t)(ch0 + cc) * T + ts + p4));
                }
            }
        }

        if (j == nch - 1) final_state[ch0 + lane] = s;
#undef PF
#undef CM
    } else {
        // ---- exact outputs path ----
        int tid = blockIdx.x * blockDim.x + threadIdx.x;
        int total = B * nch;
        if (tid >= total) return;
        int b = tid / nch;
        int j = tid - b * nch;
        float s = sstart[(size_t)j * B + b];
        const float4* xp = (const float4*)(x + (size_t)b * T + (size_t)j * CHUNK);
        float4* op = (float4*)(out + (size_t)b * T + (size_t)j * CHUNK);
#pragma unroll 4
        for (int i = 0; i < CHUNK / 4; ++i) {
            float4 v = xp[i];
            float4 o;
            o.x = fmaf(b0, v.x, s); s = fmaf(b1, v.x, a1c * o.x);
            o.y = fmaf(b0, v.y, s); s = fmaf(b1, v.y, a1c * o.y);
            o.z = fmaf(b0, v.z, s); s = fmaf(b1, v.z, a1c * o.z);
            o.w = fmaf(b0, v.w, s); s = fmaf(b1, v.w, a1c * o.w);
            op[i] = o;
        }
    }
}

extern "C" void kernel_launch(void* const* d_in, const int* in_sizes, int n_in,
                              void* d_out, int out_size, void* d_ws, size_t ws_size,
                              hipStream_t stream) {
    const float* x     = (const float*)d_in[0];
    const float* state = (const float*)d_in[1];
    const float* b0p   = (const float*)d_in[2];
    const float* b1p   = (const float*)d_in[3];
    const float* a1p   = (const float*)d_in[4];

    int B = in_sizes[1];                 // 4096
    int T = in_sizes[0] / B;             // 16384
    int nch = T / CHUNK;                 // 64

    float* out         = (float*)d_out;                   // [B][T]
    float* final_state = (float*)d_out + (size_t)B * T;   // [B]

    // ws layout: partial [nch][B]; then sstart [nch][B]
    float* partial = (float*)d_ws;
    float* sstart  = partial + (size_t)nch * B;

    int allow = (B % 64 == 0) && (T % CHUNK == 0) && (nch % BLKW == 0) &&
                (nch * CHUNK == T);

    int total = B * nch;
    int grid_fast  = allow ? (B / 64) * (nch / BLKW) : 0;
    int grid_exact = (total + BLKT - 1) / BLKT;
    int grid_main  = grid_exact > grid_fast ? grid_exact : grid_fast;

    // exact fallback (early-exits in fast mode)
    k_partials<<<(total + 255) / 256, 256, 0, stream>>>(x, b0p, b1p, a1p, partial,
                                                        B, T, nch, allow);
    k_scan<<<(B + 255) / 256, 256, 0, stream>>>(partial, state, a1p,
                                                sstart, final_state, B, nch, allow);
    // main: fast fused path or exact outputs
    k_main<<<grid_main, BLKT, 0, stream>>>(x, state, b0p, b1p, a1p, sstart,
                                           out, final_state, B, T, nch, allow);
}